// Round 3
// baseline (221.849 us; speedup 1.0000x reference)
//
#include <hip/hip_runtime.h>
#include <math.h>

// Problem constants (from reference)
#define BB   32
#define HH   112
#define WW   112
#define AA   9
#define NBOX 24
#define NBOXES (BB*NBOX)            // 768
#define NCELLS (BB*HH*WW*AA)        // 3,612,672
#define BLK   256
#define GRID  (NCELLS/4/BLK)        // 3528 exactly (each thread: 4 cells = 20 floats)

__device__ __forceinline__ float softplusf(float x) {
    // stable: log(1+e^x) = max(x,0) + log1p(exp(-|x|))
    return fmaxf(x, 0.0f) + log1pf(expf(-fabsf(x)));
}

// Single fused kernel.
//  - block 0 first computes the sparse (responsible-cell) sums into d_ws;
//    this latency-bound work hides under the other blocks' dense work.
//  - all blocks: dense softplus(obj) partial via shuffle reduce -> partials[bid]
//  - last block to finish folds partials + sparse sums, writes the 5 outputs.
__global__ __launch_bounds__(BLK) void fused_loss_kernel(
        const float* __restrict__ pred, const float* __restrict__ bboxes,
        unsigned* __restrict__ counter, double* __restrict__ sparse3,
        int* __restrict__ scnt, double* __restrict__ partials,
        float* __restrict__ out)
{
    const int t = threadIdx.x;
    const int bid = blockIdx.x;

    __shared__ int           s_key[NBOXES];
    __shared__ unsigned char s_val[NBOXES];
    __shared__ float         s_tv[NBOXES][4];
    __shared__ double        sm[4];
    __shared__ double        sred[3][4];
    __shared__ int           sredc[4];
    __shared__ unsigned      s_last;

    if (bid == 0) {
        // ---- sparse phase: 768 boxes over 256 threads (3 each) ----
        for (int b = t; b < NBOXES; b += BLK) {
            const float* bb = bboxes + b * 4;
            float cx = bb[0], cy = bb[1], w = bb[2], h = bb[3];
            bool valid = (cx != 0.f) || (cy != 0.f) || (w != 0.f) || (h != 0.f);
            int gx = min(max((int)floorf(cx * (float)WW), 0), WW - 1);
            int gy = min(max((int)floorf(cy * (float)HH), 0), HH - 1);
            // anchors: (s*sqrt(r)/224, s/sqrt(r)/224) in f64 -> f32
            float best_iou = -1.f; int best = 0; float aw_b = 1.f, ah_b = 1.f;
            const double ss[3] = {32.0, 64.0, 128.0};
            const double rr[3] = {0.5, 1.0, 2.0};
            #pragma unroll
            for (int i = 0; i < 3; ++i) {
                #pragma unroll
                for (int j = 0; j < 3; ++j) {
                    float aw = (float)(ss[i] * sqrt(rr[j]) / 224.0);
                    float ah = (float)(ss[i] / sqrt(rr[j]) / 224.0);
                    float inter = fminf(w, aw) * fminf(h, ah);
                    float uni = w * h + aw * ah - inter;
                    float iou = inter / (uni + 1e-16f);
                    if (iou > best_iou) { best_iou = iou; best = i*3+j; aw_b = aw; ah_b = ah; }
                }
            }
            s_key[b] = (gy * WW + gx) * AA + best;
            s_val[b] = valid ? 1 : 0;
            s_tv[b][0] = cx * (float)WW - (float)gx;
            s_tv[b][1] = cy * (float)HH - (float)gy;
            s_tv[b][2] = logf(w / aw_b + 1e-16f);
            s_tv[b][3] = logf(h / ah_b + 1e-16f);
        }
        __syncthreads();

        // winner resolution (last write wins within a batch) + gather
        double csum = 0.0, osum = 0.0, nsub = 0.0; int cnt = 0;
        for (int b = t; b < NBOXES; b += BLK) {
            if (!s_val[b]) continue;
            const int batch = b / NBOX;
            const int bend = (batch + 1) * NBOX;
            const int key = s_key[b];
            bool win = true;
            for (int m = b + 1; m < bend; ++m)
                if (s_val[m] && s_key[m] == key) { win = false; break; }
            if (!win) continue;
            const size_t cell = (size_t)batch * (HH*WW*AA) + (size_t)key;
            const float* p = pred + cell * 5;
            float d0 = p[0] - s_tv[b][0], d1 = p[1] - s_tv[b][1];
            float d2 = p[2] - s_tv[b][2], d3 = p[3] - s_tv[b][3];
            csum += (double)d0*d0 + (double)d1*d1 + (double)d2*d2 + (double)d3*d3;
            osum += (double)softplusf(-p[4]);
            nsub += (double)softplusf(p[4]);
            cnt  += 1;
        }
        #pragma unroll
        for (int off = 32; off; off >>= 1) {
            csum += __shfl_down(csum, off);
            osum += __shfl_down(osum, off);
            nsub += __shfl_down(nsub, off);
            cnt  += __shfl_down(cnt,  off);
        }
        if ((t & 63) == 0) { int w = t >> 6; sred[0][w]=csum; sred[1][w]=osum; sred[2][w]=nsub; sredc[w]=cnt; }
        __syncthreads();
        if (t == 0) {
            sparse3[0] = sred[0][0]+sred[0][1]+sred[0][2]+sred[0][3];
            sparse3[1] = sred[1][0]+sred[1][1]+sred[1][2]+sred[1][3];
            sparse3[2] = sred[2][0]+sred[2][1]+sred[2][2]+sred[2][3];
            scnt[0]    = sredc[0]+sredc[1]+sredc[2]+sredc[3];
        }
    }

    // ---- dense phase (all blocks): 4 cells per thread, branch-free ----
    // obj elements of the 4 cells are float4 indices 5t+{1,2,3,4}, lanes x/y/z/w.
    const int gt = bid * BLK + t;
    const float4* p4 = (const float4*)pred + (size_t)gt * 5;
    float4 va = p4[1], vb = p4[2], vc = p4[3], vd = p4[4];
    double acc = (double)softplusf(va.x) + (double)softplusf(vb.y)
               + (double)softplusf(vc.z) + (double)softplusf(vd.w);
    #pragma unroll
    for (int off = 32; off; off >>= 1) acc += __shfl_down(acc, off);
    if ((t & 63) == 0) sm[t >> 6] = acc;
    __syncthreads();
    if (t == 0) {
        partials[bid] = sm[0] + sm[1] + sm[2] + sm[3];
        __threadfence();                       // release partials (device scope)
        unsigned old = atomicAdd(counter, 1u);
        s_last = (old == (unsigned)(GRID - 1)) ? 1u : 0u;
    }
    __syncthreads();

    // ---- last block: fold everything, finalize ----
    if (s_last) {
        __threadfence();                       // acquire all partials + sparse
        double psum = 0.0;
        for (int i = t; i < GRID; i += BLK) psum += partials[i];
        #pragma unroll
        for (int off = 32; off; off >>= 1) psum += __shfl_down(psum, off);
        __syncthreads();                       // safe to reuse sm now
        if ((t & 63) == 0) sm[t >> 6] = psum;
        __syncthreads();
        if (t == 0) {
            double S = sm[0] + sm[1] + sm[2] + sm[3];
            int n_pos = scnt[0];
            double dp = fmax((double)n_pos, 1.0);
            double dn = fmax((double)NCELLS - (double)n_pos, 1.0);
            float coord = (float)(5.0 * sparse3[0] / dp);
            float obj   = (float)(sparse3[1] / dp);
            float noobj = (float)(0.5 * (S - sparse3[2]) / dn);
            out[0] = coord + obj + noobj;
            out[1] = coord;
            out[2] = obj;
            out[3] = noobj;
            out[4] = 0.0f;
        }
    }
}

extern "C" void kernel_launch(void* const* d_in, const int* in_sizes, int n_in,
                              void* d_out, int out_size, void* d_ws, size_t ws_size,
                              hipStream_t stream) {
    const float* pred   = (const float*)d_in[0];
    const float* bboxes = (const float*)d_in[1];

    // d_ws layout: [0..3] counter | [16..39] 3 doubles sparse | [48..51] cnt |
    //              [64..] partials[3528] doubles  (~28 KB total)
    char* ws = (char*)d_ws;
    unsigned* counter = (unsigned*)ws;
    double*   sparse3 = (double*)(ws + 16);
    int*      scnt    = (int*)(ws + 48);
    double*   partials= (double*)(ws + 64);

    // counter must start at 0 (harness poisons d_ws with 0xAA)
    hipMemsetAsync(d_ws, 0, 64, stream);

    hipLaunchKernelGGL(fused_loss_kernel, dim3(GRID), dim3(BLK), 0, stream,
                       pred, bboxes, counter, sparse3, scnt, partials,
                       (float*)d_out);
}

// Round 4
// 108.212 us; speedup vs baseline: 2.0501x; 2.0501x over previous
//
#include <hip/hip_runtime.h>
#include <math.h>

// Problem constants (from reference)
#define BB   32
#define HH   112
#define WW   112
#define AA   9
#define NBOX 24
#define NBOXES (BB*NBOX)            // 768
#define NCELLS (BB*HH*WW*AA)        // 3,612,672
#define BLK   256
#define GRID  (NCELLS/4/BLK)        // 3528 exactly (each thread: 4 cells = 20 floats)

__device__ __forceinline__ float softplusf(float x) {
    // stable: log(1+e^x) = max(x,0) + log1p(exp(-|x|))
    return fmaxf(x, 0.0f) + log1pf(expf(-fabsf(x)));
}

// Kernel A: dense softplus(obj) partial per block (plain store to partials[]),
// plus block 0 computes the sparse responsible-cell sums (plain stores).
// NO fences, NO atomics — the kernel boundary orders everything for kernel B.
// (Round-3 lesson: per-block device-scope fence + contended counter cost
//  ~40 ns/block serialized across XCDs = 140+ us at this grid size.)
__global__ __launch_bounds__(BLK) void dense_sparse_kernel(
        const float* __restrict__ pred, const float* __restrict__ bboxes,
        double* __restrict__ sparse3, int* __restrict__ scnt,
        double* __restrict__ partials)
{
    const int t = threadIdx.x;
    const int bid = blockIdx.x;

    __shared__ int           s_key[NBOXES];
    __shared__ unsigned char s_val[NBOXES];
    __shared__ float         s_tv[NBOXES][4];
    __shared__ double        sm[4];
    __shared__ double        sred[3][4];
    __shared__ int           sredc[4];

    if (bid == 0) {
        // ---- sparse phase: 768 boxes over 256 threads (3 each) ----
        for (int b = t; b < NBOXES; b += BLK) {
            const float* bb = bboxes + b * 4;
            float cx = bb[0], cy = bb[1], w = bb[2], h = bb[3];
            bool valid = (cx != 0.f) || (cy != 0.f) || (w != 0.f) || (h != 0.f);
            int gx = min(max((int)floorf(cx * (float)WW), 0), WW - 1);
            int gy = min(max((int)floorf(cy * (float)HH), 0), HH - 1);
            // anchors: (s*sqrt(r)/224, s/sqrt(r)/224) in f64 -> f32
            float best_iou = -1.f; int best = 0; float aw_b = 1.f, ah_b = 1.f;
            const double ss[3] = {32.0, 64.0, 128.0};
            const double rr[3] = {0.5, 1.0, 2.0};
            #pragma unroll
            for (int i = 0; i < 3; ++i) {
                #pragma unroll
                for (int j = 0; j < 3; ++j) {
                    float aw = (float)(ss[i] * sqrt(rr[j]) / 224.0);
                    float ah = (float)(ss[i] / sqrt(rr[j]) / 224.0);
                    float inter = fminf(w, aw) * fminf(h, ah);
                    float uni = w * h + aw * ah - inter;
                    float iou = inter / (uni + 1e-16f);
                    if (iou > best_iou) { best_iou = iou; best = i*3+j; aw_b = aw; ah_b = ah; }
                }
            }
            s_key[b] = (gy * WW + gx) * AA + best;
            s_val[b] = valid ? 1 : 0;
            s_tv[b][0] = cx * (float)WW - (float)gx;
            s_tv[b][1] = cy * (float)HH - (float)gy;
            s_tv[b][2] = logf(w / aw_b + 1e-16f);
            s_tv[b][3] = logf(h / ah_b + 1e-16f);
        }
        __syncthreads();

        // winner resolution (last write wins within a batch) + gather
        double csum = 0.0, osum = 0.0, nsub = 0.0; int cnt = 0;
        for (int b = t; b < NBOXES; b += BLK) {
            if (!s_val[b]) continue;
            const int batch = b / NBOX;
            const int bend = (batch + 1) * NBOX;
            const int key = s_key[b];
            bool win = true;
            for (int m = b + 1; m < bend; ++m)
                if (s_val[m] && s_key[m] == key) { win = false; break; }
            if (!win) continue;
            const size_t cell = (size_t)batch * (HH*WW*AA) + (size_t)key;
            const float* p = pred + cell * 5;
            float d0 = p[0] - s_tv[b][0], d1 = p[1] - s_tv[b][1];
            float d2 = p[2] - s_tv[b][2], d3 = p[3] - s_tv[b][3];
            csum += (double)d0*d0 + (double)d1*d1 + (double)d2*d2 + (double)d3*d3;
            osum += (double)softplusf(-p[4]);
            nsub += (double)softplusf(p[4]);
            cnt  += 1;
        }
        #pragma unroll
        for (int off = 32; off; off >>= 1) {
            csum += __shfl_down(csum, off);
            osum += __shfl_down(osum, off);
            nsub += __shfl_down(nsub, off);
            cnt  += __shfl_down(cnt,  off);
        }
        if ((t & 63) == 0) { int w = t >> 6; sred[0][w]=csum; sred[1][w]=osum; sred[2][w]=nsub; sredc[w]=cnt; }
        __syncthreads();
        if (t == 0) {
            sparse3[0] = sred[0][0]+sred[0][1]+sred[0][2]+sred[0][3];
            sparse3[1] = sred[1][0]+sred[1][1]+sred[1][2]+sred[1][3];
            sparse3[2] = sred[2][0]+sred[2][1]+sred[2][2]+sred[2][3];
            scnt[0]    = sredc[0]+sredc[1]+sredc[2]+sredc[3];
        }
    }

    // ---- dense phase (all blocks): 4 cells per thread, branch-free ----
    // obj elements of the 4 cells are float4 indices 5t+{1,2,3,4}, lanes x/y/z/w.
    const int gt = bid * BLK + t;
    const float4* p4 = (const float4*)pred + (size_t)gt * 5;
    float4 va = p4[1], vb = p4[2], vc = p4[3], vd = p4[4];
    double acc = (double)softplusf(va.x) + (double)softplusf(vb.y)
               + (double)softplusf(vc.z) + (double)softplusf(vd.w);
    #pragma unroll
    for (int off = 32; off; off >>= 1) acc += __shfl_down(acc, off);
    if ((t & 63) == 0) sm[t >> 6] = acc;
    __syncthreads();
    if (t == 0) partials[bid] = sm[0] + sm[1] + sm[2] + sm[3];
}

// Kernel B: pure fold + finalize. 1024 threads, one block.
__global__ __launch_bounds__(1024) void finalize_kernel(
        const double* __restrict__ partials,
        const double* __restrict__ sparse3, const int* __restrict__ scnt,
        float* __restrict__ out)
{
    const int t = threadIdx.x;
    __shared__ double sw[16];

    double psum = 0.0;
    for (int i = t; i < GRID; i += 1024) psum += partials[i];
    #pragma unroll
    for (int off = 32; off; off >>= 1) psum += __shfl_down(psum, off);
    if ((t & 63) == 0) sw[t >> 6] = psum;
    __syncthreads();
    if (t == 0) {
        double S = 0.0;
        #pragma unroll
        for (int i = 0; i < 16; ++i) S += sw[i];
        int n_pos = scnt[0];
        double dp = fmax((double)n_pos, 1.0);
        double dn = fmax((double)NCELLS - (double)n_pos, 1.0);
        float coord = (float)(5.0 * sparse3[0] / dp);
        float obj   = (float)(sparse3[1] / dp);
        float noobj = (float)(0.5 * (S - sparse3[2]) / dn);
        out[0] = coord + obj + noobj;
        out[1] = coord;
        out[2] = obj;
        out[3] = noobj;
        out[4] = 0.0f;
    }
}

extern "C" void kernel_launch(void* const* d_in, const int* in_sizes, int n_in,
                              void* d_out, int out_size, void* d_ws, size_t ws_size,
                              hipStream_t stream) {
    const float* pred   = (const float*)d_in[0];
    const float* bboxes = (const float*)d_in[1];

    // d_ws layout: [0..23] 3 doubles sparse | [48..51] cnt |
    //              [64..] partials[3528] doubles  (~28 KB total)
    char* ws = (char*)d_ws;
    double*   sparse3 = (double*)ws;
    int*      scnt    = (int*)(ws + 48);
    double*   partials= (double*)(ws + 64);

    hipLaunchKernelGGL(dense_sparse_kernel, dim3(GRID), dim3(BLK), 0, stream,
                       pred, bboxes, sparse3, scnt, partials);
    hipLaunchKernelGGL(finalize_kernel, dim3(1), dim3(1024), 0, stream,
                       partials, sparse3, scnt, (float*)d_out);
}